// Round 7
// baseline (171.633 us; speedup 1.0000x reference)
//
#include <hip/hip_runtime.h>
#include <math.h>

#define N_EMBD 512
#define N_HEAD 8
#define SEQ_T  2048
#define BATCH  4
#define QKV_LD 1536

typedef __attribute__((ext_vector_type(8))) short bf16x8;  // 8 bf16 (4 VGPRs)
typedef __attribute__((ext_vector_type(4))) float f32x4;

#define CL 0.18033688f   // 0.125 * log2(e)

__device__ __forceinline__ unsigned short f2bf(float f) {
    union { float f; unsigned int u; } x; x.f = f;
    return (unsigned short)((x.u + 0x7FFFu + ((x.u >> 16) & 1u)) >> 16);  // RNE
}
// pack trunc-bf16(a) | trunc-bf16(b)<<16 in ONE v_perm
__device__ __forceinline__ unsigned pack_trunc(float a, float b) {
    union { float f; unsigned u; } x, y; x.f = a; y.f = b;
    return __builtin_amdgcn_perm(y.u, x.u, 0x07060302u);
}
// bf16x8 * scalar (unpack, mul, RNE repack) — once per block for Q
__device__ __forceinline__ bf16x8 scale_frag(bf16x8 v, float c) {
    bf16x8 r;
    #pragma unroll
    for (int i = 0; i < 8; ++i) {
        union { unsigned u; float f; } x;
        x.u = ((unsigned)(unsigned short)v[i]) << 16;
        r[i] = (short)f2bf(x.f * c);
    }
    return r;
}

// async global->LDS, 16B per lane; dest = wave-uniform base + lane*16
__device__ __forceinline__ void gl_lds16(const void* g, void* s) {
    __builtin_amdgcn_global_load_lds(
        (const __attribute__((address_space(1))) void*)g,
        (__attribute__((address_space(3))) void*)s, 16, 0, 0);
}

// ---------------------------------------------------------------------------
// prep: [0,2048) cvt x fp32->bf16 ; [2048,2816) transpose attn_w ;
//       [2816,3072) transpose proj_w
// ---------------------------------------------------------------------------
__global__ __launch_bounds__(256) void prep(
    const float* __restrict__ x,  unsigned short* __restrict__ x_bf,
    const float* __restrict__ w1, unsigned short* __restrict__ w1t,
    const float* __restrict__ w2, unsigned short* __restrict__ w2t)
{
    __shared__ float t[32][33];
    const int bx = blockIdx.x, tid = threadIdx.x;
    if (bx < 2048) {
        const int i = bx * 256 + tid;
        const float4 a = ((const float4*)x)[i * 2 + 0];
        const float4 b = ((const float4*)x)[i * 2 + 1];
        union { unsigned short u[8]; uint4 v; } r;
        r.u[0]=f2bf(a.x); r.u[1]=f2bf(a.y); r.u[2]=f2bf(a.z); r.u[3]=f2bf(a.w);
        r.u[4]=f2bf(b.x); r.u[5]=f2bf(b.y); r.u[6]=f2bf(b.z); r.u[7]=f2bf(b.w);
        ((uint4*)x_bf)[i] = r.v;
        return;
    }
    const float* W; unsigned short* Wt; int N, tt;
    if (bx < 2816) { tt = bx - 2048; W = w1; Wt = w1t; N = 1536; }
    else           { tt = bx - 2816; W = w2; Wt = w2t; N = 512; }
    const int nb = (bx < 2816) ? 48 : 16;
    const int n0 = (tt % nb) * 32, k0 = (tt / nb) * 32;
    const int tx = tid & 31, ty = tid >> 5;
    #pragma unroll
    for (int i = 0; i < 4; ++i)
        t[ty + i * 8][tx] = W[(size_t)(k0 + ty + i * 8) * N + n0 + tx];
    __syncthreads();
    #pragma unroll
    for (int i = 0; i < 4; ++i)
        Wt[(size_t)(n0 + ty + i * 8) * 512 + k0 + tx] = f2bf(t[tx][ty + i * 8]);
}

// ---------------------------------------------------------------------------
// MFMA GEMM v3: DMA for chunk it+1 issued AFTER the top-of-iter barrier, so
// each barrier drains a DMA that had a FULL iteration in flight (R5's version
// drained the just-issued DMA -> full latency exposed; this is the fix).
// One barrier per K-iter.
// ---------------------------------------------------------------------------
template <int BM, int BN, bool BF16_OUT>
__global__ __launch_bounds__(256) void gemm_mfma(
    const unsigned short* __restrict__ A,
    const unsigned short* __restrict__ Bt,
    const float* __restrict__ bias,
    void* __restrict__ C, int N, int K)
{
    constexpr int WMT = BM / 32, WNT = BN / 32;
    constexpr int NIT_A = BM / 64, NIT_B = BN / 64;
    __shared__ unsigned short As[2][BM * 32];
    __shared__ unsigned short Bs[2][BN * 32];

    const int tid  = threadIdx.x;
    const int wave = tid >> 6, lane = tid & 63;
    const int low  = lane & 15, quad = lane >> 4;
    const int wm   = (wave & 1) * (BM / 2), wn = (wave >> 1) * (BN / 2);
    const int row0 = blockIdx.y * BM, col0 = blockIdx.x * BN;

    const unsigned short* pa[NIT_A]; int da[NIT_A];
    #pragma unroll
    for (int i = 0; i < NIT_A; ++i) {
        const int p = wave * BM + i * 64 + lane;
        const int m = p >> 2, o = p & 3;
        const int q = o ^ ((m >> 1) & 3);
        pa[i] = A + (size_t)(row0 + m) * K + q * 8;
        da[i] = (wave * BM + i * 64) * 8;
    }
    const unsigned short* pb[NIT_B]; int db[NIT_B];
    #pragma unroll
    for (int i = 0; i < NIT_B; ++i) {
        const int p = wave * BN + i * 64 + lane;
        const int m = p >> 2, o = p & 3;
        const int q = o ^ ((m >> 1) & 3);
        pb[i] = Bt + (size_t)(col0 + m) * K + q * 8;
        db[i] = (wave * BN + i * 64) * 8;
    }

    f32x4 acc[WMT][WNT];
    #pragma unroll
    for (int i = 0; i < WMT; ++i)
        #pragma unroll
        for (int j = 0; j < WNT; ++j) acc[i][j] = (f32x4){0.f, 0.f, 0.f, 0.f};

    // prime chunk 0 into buffer 0
    #pragma unroll
    for (int i = 0; i < NIT_A; ++i) gl_lds16(pa[i], &As[0][da[i]]);
    #pragma unroll
    for (int i = 0; i < NIT_B; ++i) gl_lds16(pb[i], &Bs[0][db[i]]);

    const int NIT = K >> 5;
    for (int it = 0; it < NIT; ++it) {
        const int cur = it & 1;
        __syncthreads();   // drains DMA(it) [issued a full iter ago]; read-fence for buf cur^1
        if (it + 1 < NIT) {
            const int ko = (it + 1) * 32;
            #pragma unroll
            for (int i = 0; i < NIT_A; ++i) gl_lds16(pa[i] + ko, &As[cur ^ 1][da[i]]);
            #pragma unroll
            for (int i = 0; i < NIT_B; ++i) gl_lds16(pb[i] + ko, &Bs[cur ^ 1][db[i]]);
        }
        const int swz = (low >> 1) & 3;
        bf16x8 af[WMT], bfr[WNT];
        #pragma unroll
        for (int t = 0; t < WMT; ++t)
            af[t] = *(const bf16x8*)&As[cur][(wm + t * 16 + low) * 32 + ((quad ^ swz) * 8)];
        #pragma unroll
        for (int t = 0; t < WNT; ++t)
            bfr[t] = *(const bf16x8*)&Bs[cur][(wn + t * 16 + low) * 32 + ((quad ^ swz) * 8)];
        #pragma unroll
        for (int i = 0; i < WMT; ++i)
            #pragma unroll
            for (int j = 0; j < WNT; ++j)
                acc[i][j] = __builtin_amdgcn_mfma_f32_16x16x32_bf16(
                    af[i], bfr[j], acc[i][j], 0, 0, 0);
    }

    float bv[WNT];
    #pragma unroll
    for (int j = 0; j < WNT; ++j) bv[j] = bias[col0 + wn + j * 16 + low];
    #pragma unroll
    for (int i = 0; i < WMT; ++i)
        #pragma unroll
        for (int r = 0; r < 4; ++r) {
            const size_t row = row0 + wm + i * 16 + quad * 4 + r;
            #pragma unroll
            for (int j = 0; j < WNT; ++j) {
                const int col = col0 + wn + j * 16 + low;
                const float v = acc[i][j][r] + bv[j];
                if (BF16_OUT)
                    ((unsigned short*)C)[row * N + col] = f2bf(v);
                else
                    ((float*)C)[row * N + col] = v;
            }
        }
}

// ---------------------------------------------------------------------------
// attention v6: 2-slot balanced work-list.
// Block pa owns q-tiles A=pa, B=31-pa: 33 (tile,kc) items total; slot0 runs
// even items, slot1 odd -> EVERY block runs exactly 17 iterations. Max-free
// softmax makes chunk order/grouping irrelevant (linear accumulation).
// K/V staged via regs -> ds_write (single buffer per slot); global prefetch
// for iter i+1 is consumed after iter i+1's first barrier => no barrier ever
// drains an in-flight load. K layout [64][72] (R2-verified), V layout as R4.
// ---------------------------------------------------------------------------
template <bool MASK>
__device__ __forceinline__ void tile_step(
    const bf16x8 kf[4][2], const bf16x8 qf0, const bf16x8 qf1,
    int thr, int quad, int low, unsigned short* ps)
{
    f32x4 s[4];
    #pragma unroll
    for (int st = 0; st < 4; ++st) {
        f32x4 a = (f32x4){0.f, 0.f, 0.f, 0.f};
        a = __builtin_amdgcn_mfma_f32_16x16x32_bf16(kf[st][0], qf0, a, 0, 0, 0);
        a = __builtin_amdgcn_mfma_f32_16x16x32_bf16(kf[st][1], qf1, a, 0, 0, 0);
        s[st] = a;
    }
    #pragma unroll
    for (int st = 0; st < 4; ++st) {
        float p[4];
        #pragma unroll
        for (int r = 0; r < 4; ++r) {
            float v = s[st][r];
            if (MASK) v = (st * 16 + r <= thr) ? v : -1e30f;  // exp2 -> 0
            p[r] = __builtin_amdgcn_exp2f(v);
        }
        uint2 pk;
        pk.x = pack_trunc(p[0], p[1]);
        pk.y = pack_trunc(p[2], p[3]);
        *(uint2*)&ps[low * 72 + st * 16 + quad * 4] = pk;
    }
}

__device__ __forceinline__ void pv_step(
    const bf16x8 vf[4][2], const unsigned short* ps, int quad, int low,
    f32x4* o, f32x4& lacc, const bf16x8 ones)
{
    const bf16x8 p0 = *(const bf16x8*)&ps[low * 72 + quad * 8];
    const bf16x8 p1 = *(const bf16x8*)&ps[low * 72 + quad * 8 + 32];
    #pragma unroll
    for (int t = 0; t < 4; ++t) {
        o[t] = __builtin_amdgcn_mfma_f32_16x16x32_bf16(p0, vf[t][0], o[t], 0, 0, 0);
        o[t] = __builtin_amdgcn_mfma_f32_16x16x32_bf16(p1, vf[t][1], o[t], 0, 0, 0);
    }
    lacc = __builtin_amdgcn_mfma_f32_16x16x32_bf16(p0, ones, lacc, 0, 0, 0);
    lacc = __builtin_amdgcn_mfma_f32_16x16x32_bf16(p1, ones, lacc, 0, 0, 0);
}

template <bool MASK>
__device__ __forceinline__ void do_item(
    const unsigned short* ksb, const unsigned short* vtb, unsigned short* ps,
    const bf16x8 qf0, const bf16x8 qf1, int thr, int quad, int low,
    f32x4 (&o)[4], f32x4& l, const bf16x8 ones)
{
    bf16x8 kf[4][2];
    #pragma unroll
    for (int t = 0; t < 4; ++t)
        #pragma unroll
        for (int i = 0; i < 2; ++i)
            kf[t][i] = *(const bf16x8*)&ksb[(t * 16 + low) * 72 + (quad + 4 * i) * 8];
    tile_step<MASK>(kf, qf0, qf1, thr, quad, low, ps);
    asm volatile("" ::: "memory");   // per-wave Ps: program order + fence
    bf16x8 vf[4][2];
    #pragma unroll
    for (int t = 0; t < 4; ++t)
        #pragma unroll
        for (int i = 0; i < 2; ++i)
            vf[t][i] = *(const bf16x8*)
                &vtb[((t * 16 + low) << 6) + (((quad + 4 * i) ^ (low & 7)) << 3)];
    pv_step(vf, ps, quad, low, o, l, ones);
}

__global__ __launch_bounds__(256) void attn_mfma(
    const unsigned short* __restrict__ qkv,   // bf16 [8192][1536]
    unsigned short* __restrict__ y)           // bf16 [8192][512]
{
    const int bh  = blockIdx.y;
    const int b   = bh >> 3, h = bh & 7;
    const int pa  = blockIdx.x;               // 0..15
    const int qA0 = pa * 64;
    const int qB0 = (31 - pa) * 64;
    const int nA  = pa + 1;                   // items: [A0..A(nA-1), B0..B(32-nA)]
    const int tid = threadIdx.x;
    const int wave = tid >> 6, lane = tid & 63;
    const int low  = lane & 15, quad = lane >> 4;

    __shared__ unsigned short Ks[2][64 * 72];   // [slot][key][d], pad 8
    __shared__ unsigned short Vt[2][64 * 64];   // [slot][d][key], oct-xor (R4)
    __shared__ unsigned short Ps[2][4][16 * 72];

    const size_t base = (size_t)b * SEQ_T * QKV_LD + h * 64;
    const unsigned short* qp = qkv + base;
    const unsigned short* kp = qkv + base + 512;
    const unsigned short* vp = qkv + base + 1024;

    const int qmyA = qA0 + wave * 16 + low;
    const int qmyB = qB0 + wave * 16 + low;

    const bf16x8 qfA0 = scale_frag(*(const bf16x8*)(qp + (size_t)qmyA * QKV_LD + quad * 8), CL);
    const bf16x8 qfA1 = scale_frag(*(const bf16x8*)(qp + (size_t)qmyA * QKV_LD + quad * 8 + 32), CL);
    const bf16x8 qfB0 = scale_frag(*(const bf16x8*)(qp + (size_t)qmyB * QKV_LD + quad * 8), CL);
    const bf16x8 qfB1 = scale_frag(*(const bf16x8*)(qp + (size_t)qmyB * QKV_LD + quad * 8 + 32), CL);

    bf16x8 ones;
    #pragma unroll
    for (int i = 0; i < 8; ++i) ones[i] = (short)0x3F80;   // bf16 1.0

    f32x4 oA[4], oB[4], lA, lB;
    #pragma unroll
    for (int t = 0; t < 4; ++t) {
        oA[t] = (f32x4){0.f, 0.f, 0.f, 0.f};
        oB[t] = (f32x4){0.f, 0.f, 0.f, 0.f};
    }
    lA = (f32x4){0.f, 0.f, 0.f, 0.f};
    lB = (f32x4){0.f, 0.f, 0.f, 0.f};

    // item g -> key chunk
    #define ITEM_KC(g) (((g) < nA) ? (g) : ((g) - nA))

    // prefetch regs: slot0 <- item0, slot1 <- item1
    bf16x8 k0a, k0b, v0a, v0b, k1a, k1b, v1a, v1b;
    {
        const size_t r0 = (size_t)(ITEM_KC(0) * 64 + lane) * QKV_LD;
        k0a = *(const bf16x8*)(kp + r0 + wave * 16);
        k0b = *(const bf16x8*)(kp + r0 + wave * 16 + 8);
        v0a = *(const bf16x8*)(vp + r0 + wave * 8);
        v0b = *(const bf16x8*)(vp + r0 + wave * 8 + 32);
        const size_t r1 = (size_t)(ITEM_KC(1) * 64 + lane) * QKV_LD;
        k1a = *(const bf16x8*)(kp + r1 + wave * 16);
        k1b = *(const bf16x8*)(kp + r1 + wave * 16 + 8);
        v1a = *(const bf16x8*)(vp + r1 + wave * 8);
        v1b = *(const bf16x8*)(vp + r1 + wave * 8 + 32);
    }

    const int d0 = wave * 8;
    for (int i = 0; i < 17; ++i) {
        const int g0 = 2 * i, g1 = 2 * i + 1;

        __syncthreads();   // all waves done READING slot LDS from iter i-1

        // stage slot0 (g0 <= 32 always)
        *(bf16x8*)&Ks[0][lane * 72 + wave * 16]     = k0a;
        *(bf16x8*)&Ks[0][lane * 72 + wave * 16 + 8] = k0b;
        #pragma unroll
        for (int ii = 0; ii < 8; ++ii) {
            const int po = ((lane >> 3) ^ ii) * 8 + (lane & 7);
            Vt[0][((d0 + ii) << 6) + po]      = (unsigned short)v0a[ii];
            Vt[0][((d0 + 32 + ii) << 6) + po] = (unsigned short)v0b[ii];
        }
        if (g1 <= 32) {
            *(bf16x8*)&Ks[1][lane * 72 + wave * 16]     = k1a;
            *(bf16x8*)&Ks[1][lane * 72 + wave * 16 + 8] = k1b;
            #pragma unroll
            for (int ii = 0; ii < 8; ++ii) {
                const int po = ((lane >> 3) ^ ii) * 8 + (lane & 7);
                Vt[1][((d0 + ii) << 6) + po]      = (unsigned short)v1a[ii];
                Vt[1][((d0 + 32 + ii) << 6) + po] = (unsigned short)v1b[ii];
            }
        }
        __syncthreads();   // staged data visible

        // prefetch for iter i+1 (consumed only after next barrier pair)
        if (g0 + 2 <= 32) {
            const size_t r = (size_t)(ITEM_KC(g0 + 2) * 64 + lane) * QKV_LD;
            k0a = *(const bf16x8*)(kp + r + wave * 16);
            k0b = *(const bf16x8*)(kp + r + wave * 16 + 8);
            v0a = *(const bf16x8*)(vp + r + wave * 8);
            v0b = *(const bf16x8*)(vp + r + wave * 8 + 32);
        }
        if (g1 + 2 <= 32) {
            const size_t r = (size_t)(ITEM_KC(g1 + 2) * 64 + lane) * QKV_LD;
            k1a = *(const bf16x8*)(kp + r + wave * 16);
            k1b = *(const bf16x8*)(kp + r + wave * 16 + 8);
            v1a = *(const bf16x8*)(vp + r + wave * 8);
            v1b = *(const bf16x8*)(vp + r + wave * 8 + 32);
        }

        // compute slot0 item g0
        {
            const int kc = ITEM_KC(g0);
            const bool isA = g0 < nA;
            const bool msk = (g0 == nA - 1) || (g0 == 32);
            const int qmy = isA ? qmyA : qmyB;
            const int thr = qmy - kc * 64 - quad * 4;
            if (isA) {
                if (msk) do_item<true >(&Ks[0][0], &Vt[0][0], &Ps[0][wave][0], qfA0, qfA1, thr, quad, low, oA, lA, ones);
                else     do_item<false>(&Ks[0][0], &Vt[0][0], &Ps[0][wave][0], qfA0, qfA1, thr, quad, low, oA, lA, ones);
            } else {
                if (msk) do_item<true >(&Ks[0][0], &Vt[0][0], &Ps[0][wave][0], qfB0, qfB1, thr, quad, low, oB, lB, ones);
                else     do_item<false>(&Ks[0][0], &Vt[0][0], &Ps[0][wave][0], qfB0, qfB1, thr, quad, low, oB, lB, ones);
            }
        }
        // compute slot1 item g1
        if (g1 <= 32) {
            const int kc = ITEM_KC(g1);
            const bool isA = g1 < nA;
            const bool msk = (g1 == nA - 1) || (g1 == 32);
            const int qmy = isA ? qmyA : qmyB;
            const int thr = qmy - kc * 64 - quad * 4;
            if (isA) {
                if (msk) do_item<true >(&Ks[1][0], &Vt[1][0], &Ps[1][wave][0], qfA0, qfA1, thr, quad, low, oA, lA, ones);
                else     do_item<false>(&Ks[1][0], &Vt[1][0], &Ps[1][wave][0], qfA0, qfA1, thr, quad, low, oA, lA, ones);
            } else {
                if (msk) do_item<true >(&Ks[1][0], &Vt[1][0], &Ps[1][wave][0], qfB0, qfB1, thr, quad, low, oB, lB, ones);
                else     do_item<false>(&Ks[1][0], &Vt[1][0], &Ps[1][wave][0], qfB0, qfB1, thr, quad, low, oB, lB, ones);
            }
        }
    }
    #undef ITEM_KC

    // epilogue: shuffle-free (l in same C-layout rows as o)
    #pragma unroll
    for (int r = 0; r < 4; ++r) {
        const float rlA = 1.f / lA[r];
        const int qrow = qA0 + wave * 16 + quad * 4 + r;
        unsigned short* yp = y + (size_t)(b * SEQ_T + qrow) * N_EMBD + h * 64 + low;
        #pragma unroll
        for (int t = 0; t < 4; ++t) yp[16 * t] = f2bf(oA[t][r] * rlA);
    }
    #pragma unroll
    for (int r = 0; r < 4; ++r) {
        const float rlB = 1.f / lB[r];
        const int qrow = qB0 + wave * 16 + quad * 4 + r;
        unsigned short* yp = y + (size_t)(b * SEQ_T + qrow) * N_EMBD + h * 64 + low;
        #pragma unroll
        for (int t = 0; t < 4; ++t) yp[16 * t] = f2bf(oB[t][r] * rlB);
    }
}

// ---------------------------------------------------------------------------
extern "C" void kernel_launch(void* const* d_in, const int* in_sizes, int n_in,
                              void* d_out, int out_size, void* d_ws, size_t ws_size,
                              hipStream_t stream)
{
    const float* x      = (const float*)d_in[0];
    const float* attn_w = (const float*)d_in[1];   // [512][1536]
    const float* attn_b = (const float*)d_in[2];
    const float* proj_w = (const float*)d_in[3];   // [512][512]
    const float* proj_b = (const float*)d_in[4];
    float*       out    = (float*)d_out;

    char* ws = (char*)d_ws;
    unsigned short* qkv_bf = (unsigned short*)(ws);                      // 25.2 MB
    unsigned short* y_bf   = (unsigned short*)(ws + 25165824);           //  8.4 MB
    unsigned short* x_bf   = (unsigned short*)(ws + 33554432);           //  8.4 MB
    unsigned short* w1t    = (unsigned short*)(ws + 41943040);           //  1.6 MB
    unsigned short* w2t    = (unsigned short*)(ws + 43515904);           //  0.5 MB

    prep<<<3072, 256, 0, stream>>>(x, x_bf, attn_w, w1t, proj_w, w2t);

    gemm_mfma<128, 128, true><<<dim3(12, 64), 256, 0, stream>>>(
        x_bf, w1t, attn_b, qkv_bf, QKV_LD, N_EMBD);

    attn_mfma<<<dim3(16, BATCH * N_HEAD), 256, 0, stream>>>(qkv_bf, y_bf);

    gemm_mfma<64, 128, false><<<dim3(4, 128), 256, 0, stream>>>(
        y_bf, w2t, proj_b, out, N_EMBD, N_EMBD);
}

// Round 8
// 159.668 us; speedup vs baseline: 1.0749x; 1.0749x over previous
//
#include <hip/hip_runtime.h>
#include <math.h>

#define N_EMBD 512
#define N_HEAD 8
#define SEQ_T  2048
#define BATCH  4
#define QKV_LD 1536

typedef __attribute__((ext_vector_type(8))) short bf16x8;  // 8 bf16 (4 VGPRs)
typedef __attribute__((ext_vector_type(4))) float f32x4;

#define CL 0.18033688f   // 0.125 * log2(e)

__device__ __forceinline__ unsigned short f2bf(float f) {
    union { float f; unsigned int u; } x; x.f = f;
    return (unsigned short)((x.u + 0x7FFFu + ((x.u >> 16) & 1u)) >> 16);  // RNE
}
// pack trunc-bf16(a) | trunc-bf16(b)<<16 in ONE v_perm
__device__ __forceinline__ unsigned pack_trunc(float a, float b) {
    union { float f; unsigned u; } x, y; x.f = a; y.f = b;
    return __builtin_amdgcn_perm(y.u, x.u, 0x07060302u);
}
// bf16x8 * scalar (unpack, mul, RNE repack) — once per block for Q
__device__ __forceinline__ bf16x8 scale_frag(bf16x8 v, float c) {
    bf16x8 r;
    #pragma unroll
    for (int i = 0; i < 8; ++i) {
        union { unsigned u; float f; } x;
        x.u = ((unsigned)(unsigned short)v[i]) << 16;
        r[i] = (short)f2bf(x.f * c);
    }
    return r;
}

// async global->LDS, 16B per lane; dest = wave-uniform base + lane*16
__device__ __forceinline__ void gl_lds16(const void* g, void* s) {
    __builtin_amdgcn_global_load_lds(
        (const __attribute__((address_space(1))) void*)g,
        (__attribute__((address_space(3))) void*)s, 16, 0, 0);
}

// ---------------------------------------------------------------------------
// prep (weights only now): [0,768) transpose attn_w ; [768,1024) proj_w
// ---------------------------------------------------------------------------
__global__ __launch_bounds__(256) void prep(
    const float* __restrict__ w1, unsigned short* __restrict__ w1t,
    const float* __restrict__ w2, unsigned short* __restrict__ w2t)
{
    __shared__ float t[32][33];
    const int bx = blockIdx.x, tid = threadIdx.x;
    const float* W; unsigned short* Wt; int N, tt, nb;
    if (bx < 768) { tt = bx;       W = w1; Wt = w1t; N = 1536; nb = 48; }
    else          { tt = bx - 768; W = w2; Wt = w2t; N = 512;  nb = 16; }
    const int n0 = (tt % nb) * 32, k0 = (tt / nb) * 32;
    const int tx = tid & 31, ty = tid >> 5;
    #pragma unroll
    for (int i = 0; i < 4; ++i)
        t[ty + i * 8][tx] = W[(size_t)(k0 + ty + i * 8) * N + n0 + tx];
    __syncthreads();
    #pragma unroll
    for (int i = 0; i < 4; ++i)
        Wt[(size_t)(n0 + ty + i * 8) * 512 + k0 + tx] = f2bf(t[tx][ty + i * 8]);
}

// ---------------------------------------------------------------------------
// MFMA GEMM v4: reg-staged A and B (no global_load_lds), single LDS buffer,
// 2 barriers/iter, NEITHER waits an in-flight global load (loads for it+1
// issue during it's compute -> full-iteration slack; attn-proven pattern).
// A source optionally fp32 (converted during staging -> kills the prep x pass).
// XOR-oct LDS layout + frag-read path identical to the R3-verified GEMM.
// ---------------------------------------------------------------------------
template <int BM, int BN, bool CVT_A, bool BF16_OUT>
__global__ __launch_bounds__(256) void gemm_mfma(
    const void* __restrict__ Asrc,              // fp32 [M][K] if CVT_A else bf16
    const unsigned short* __restrict__ Bt,      // bf16 [N][K]
    const float* __restrict__ bias,
    void* __restrict__ C, int N, int K)
{
    constexpr int WMT = BM / 32, WNT = BN / 32;
    constexpr int SA = (BM * 4) / 256, SB = (BN * 4) / 256;  // octs per thread
    __shared__ unsigned short As[BM * 32];
    __shared__ unsigned short Bs[BN * 32];

    const int tid  = threadIdx.x;
    const int wave = tid >> 6, lane = tid & 63;
    const int low  = lane & 15, quad = lane >> 4;
    const int wm   = (wave & 1) * (BM / 2), wn = (wave >> 1) * (BN / 2);
    const int row0 = blockIdx.y * BM, col0 = blockIdx.x * BN;

    // staging slots: oct p -> row m = p>>2, phys slot o = p&3 holds logical
    // k-oct q = o ^ ((m>>1)&3)  (same swizzle the frag reads invert)
    size_t a_src[SA]; int a_dst[SA];
    #pragma unroll
    for (int s = 0; s < SA; ++s) {
        const int p = tid + 256 * s;
        const int m = p >> 2, o = p & 3, q = o ^ ((m >> 1) & 3);
        a_src[s] = (size_t)(row0 + m) * K + q * 8;
        a_dst[s] = m * 32 + o * 8;
    }
    size_t b_src[SB]; int b_dst[SB];
    #pragma unroll
    for (int s = 0; s < SB; ++s) {
        const int p = tid + 256 * s;
        const int m = p >> 2, o = p & 3, q = o ^ ((m >> 1) & 3);
        b_src[s] = (size_t)(col0 + m) * K + q * 8;
        b_dst[s] = m * 32 + o * 8;
    }

    f32x4 acc[WMT][WNT];
    #pragma unroll
    for (int i = 0; i < WMT; ++i)
        #pragma unroll
        for (int j = 0; j < WNT; ++j) acc[i][j] = (f32x4){0.f, 0.f, 0.f, 0.f};

    bf16x8 ar[SA], br[SB];
    const float*          af32 = (const float*)Asrc;
    const unsigned short* a16  = (const unsigned short*)Asrc;

    // load chunk 0 into regs
    #pragma unroll
    for (int s = 0; s < SA; ++s) {
        if (CVT_A) {
            const float4 f0 = *(const float4*)(af32 + a_src[s]);
            const float4 f1 = *(const float4*)(af32 + a_src[s] + 4);
            union { uint4 v; bf16x8 h; } u;
            u.v.x = pack_trunc(f0.x, f0.y); u.v.y = pack_trunc(f0.z, f0.w);
            u.v.z = pack_trunc(f1.x, f1.y); u.v.w = pack_trunc(f1.z, f1.w);
            ar[s] = u.h;
        } else {
            ar[s] = *(const bf16x8*)(a16 + a_src[s]);
        }
    }
    #pragma unroll
    for (int s = 0; s < SB; ++s) br[s] = *(const bf16x8*)(Bt + b_src[s]);

    const int NIT = K >> 5;
    for (int it = 0; it < NIT; ++it) {
        __syncthreads();   // prev iter's frag reads done (buffers free)
        #pragma unroll
        for (int s = 0; s < SA; ++s) *(bf16x8*)&As[a_dst[s]] = ar[s];
        #pragma unroll
        for (int s = 0; s < SB; ++s) *(bf16x8*)&Bs[b_dst[s]] = br[s];
        __syncthreads();   // staged tile visible (waits only LDS writes)

        if (it + 1 < NIT) {   // global loads for it+1: full iter of slack
            const int ko = (it + 1) * 32;
            #pragma unroll
            for (int s = 0; s < SA; ++s) {
                if (CVT_A) {
                    const float4 f0 = *(const float4*)(af32 + a_src[s] + ko);
                    const float4 f1 = *(const float4*)(af32 + a_src[s] + ko + 4);
                    union { uint4 v; bf16x8 h; } u;
                    u.v.x = pack_trunc(f0.x, f0.y); u.v.y = pack_trunc(f0.z, f0.w);
                    u.v.z = pack_trunc(f1.x, f1.y); u.v.w = pack_trunc(f1.z, f1.w);
                    ar[s] = u.h;
                } else {
                    ar[s] = *(const bf16x8*)(a16 + a_src[s] + ko);
                }
            }
            #pragma unroll
            for (int s = 0; s < SB; ++s) br[s] = *(const bf16x8*)(Bt + b_src[s] + ko);
        }

        const int swz = (low >> 1) & 3;
        bf16x8 af[WMT], bfr[WNT];
        #pragma unroll
        for (int t = 0; t < WMT; ++t)
            af[t] = *(const bf16x8*)&As[(wm + t * 16 + low) * 32 + ((quad ^ swz) * 8)];
        #pragma unroll
        for (int t = 0; t < WNT; ++t)
            bfr[t] = *(const bf16x8*)&Bs[(wn + t * 16 + low) * 32 + ((quad ^ swz) * 8)];
        #pragma unroll
        for (int i = 0; i < WMT; ++i)
            #pragma unroll
            for (int j = 0; j < WNT; ++j)
                acc[i][j] = __builtin_amdgcn_mfma_f32_16x16x32_bf16(
                    af[i], bfr[j], acc[i][j], 0, 0, 0);
    }

    float bv[WNT];
    #pragma unroll
    for (int j = 0; j < WNT; ++j) bv[j] = bias[col0 + wn + j * 16 + low];
    #pragma unroll
    for (int i = 0; i < WMT; ++i)
        #pragma unroll
        for (int r = 0; r < 4; ++r) {
            const size_t row = row0 + wm + i * 16 + quad * 4 + r;
            #pragma unroll
            for (int j = 0; j < WNT; ++j) {
                const int col = col0 + wn + j * 16 + low;
                const float v = acc[i][j][r] + bv[j];
                if (BF16_OUT)
                    ((unsigned short*)C)[row * N + col] = f2bf(v);
                else
                    ((float*)C)[row * N + col] = v;
            }
        }
}

// ---------------------------------------------------------------------------
// attention v5 (R6 kernel, verbatim — 51.9 us proven): paired q-tiles with
// SHARED chunk stream, double-buffered K (gl_lds) / V (reg scatter),
// one barrier per chunk, no-max softmax, ones-MFMA l, shuffle-free epilogue.
// ---------------------------------------------------------------------------
template <bool MASK>
__device__ __forceinline__ void tile_step(
    const bf16x8 kf[4][2], const bf16x8 qf0, const bf16x8 qf1,
    int thr, int quad, int low, unsigned short* ps)
{
    f32x4 s[4];
    #pragma unroll
    for (int st = 0; st < 4; ++st) {
        f32x4 a = (f32x4){0.f, 0.f, 0.f, 0.f};
        a = __builtin_amdgcn_mfma_f32_16x16x32_bf16(kf[st][0], qf0, a, 0, 0, 0);
        a = __builtin_amdgcn_mfma_f32_16x16x32_bf16(kf[st][1], qf1, a, 0, 0, 0);
        s[st] = a;
    }
    #pragma unroll
    for (int st = 0; st < 4; ++st) {
        float p[4];
        #pragma unroll
        for (int r = 0; r < 4; ++r) {
            float v = s[st][r];
            if (MASK) v = (st * 16 + r <= thr) ? v : -1e30f;  // exp2 -> 0
            p[r] = __builtin_amdgcn_exp2f(v);
        }
        uint2 pk;
        pk.x = pack_trunc(p[0], p[1]);
        pk.y = pack_trunc(p[2], p[3]);
        *(uint2*)&ps[low * 72 + st * 16 + quad * 4] = pk;
    }
}

__device__ __forceinline__ void pv_step(
    const bf16x8 vf[4][2], const unsigned short* ps, int quad, int low,
    f32x4* o, f32x4& lacc, const bf16x8 ones)
{
    const bf16x8 p0 = *(const bf16x8*)&ps[low * 72 + quad * 8];
    const bf16x8 p1 = *(const bf16x8*)&ps[low * 72 + quad * 8 + 32];
    #pragma unroll
    for (int t = 0; t < 4; ++t) {
        o[t] = __builtin_amdgcn_mfma_f32_16x16x32_bf16(p0, vf[t][0], o[t], 0, 0, 0);
        o[t] = __builtin_amdgcn_mfma_f32_16x16x32_bf16(p1, vf[t][1], o[t], 0, 0, 0);
    }
    lacc = __builtin_amdgcn_mfma_f32_16x16x32_bf16(p0, ones, lacc, 0, 0, 0);
    lacc = __builtin_amdgcn_mfma_f32_16x16x32_bf16(p1, ones, lacc, 0, 0, 0);
}

__global__ __launch_bounds__(256) void attn_mfma(
    const unsigned short* __restrict__ qkv,   // bf16 [8192][1536]
    unsigned short* __restrict__ y)           // bf16 [8192][512]
{
    const int bh  = blockIdx.y;
    const int b   = bh >> 3, h = bh & 7;
    const int pa  = blockIdx.x;               // 0..15
    const int qA0 = pa * 64;
    const int qB0 = (31 - pa) * 64;
    const int nA  = pa + 1, nB = 32 - pa;
    const int tid = threadIdx.x;
    const int wave = tid >> 6, lane = tid & 63;
    const int low  = lane & 15, quad = lane >> 4;

    __shared__ unsigned short Ks[2][64 * 64];
    __shared__ unsigned short Vt[2][64 * 64];
    __shared__ unsigned short PsA[4][16 * 72];
    __shared__ unsigned short PsB[4][16 * 72];

    const size_t base = (size_t)b * SEQ_T * QKV_LD + h * 64;
    const unsigned short* qp = qkv + base;
    const unsigned short* kp = qkv + base + 512;
    const unsigned short* vp = qkv + base + 1024;

    const int qmyA = qA0 + wave * 16 + low;
    const int qmyB = qB0 + wave * 16 + low;

    const bf16x8 qfA0 = scale_frag(*(const bf16x8*)(qp + (size_t)qmyA * QKV_LD + quad * 8), CL);
    const bf16x8 qfA1 = scale_frag(*(const bf16x8*)(qp + (size_t)qmyA * QKV_LD + quad * 8 + 32), CL);
    const bf16x8 qfB0 = scale_frag(*(const bf16x8*)(qp + (size_t)qmyB * QKV_LD + quad * 8), CL);
    const bf16x8 qfB1 = scale_frag(*(const bf16x8*)(qp + (size_t)qmyB * QKV_LD + quad * 8 + 32), CL);

    bf16x8 ones;
    #pragma unroll
    for (int i = 0; i < 8; ++i) ones[i] = (short)0x3F80;   // bf16 1.0

    const int d0 = wave * 8;
    unsigned short* psA = &PsA[wave][0];
    unsigned short* psB = &PsB[wave][0];

    bf16x8 vr0 = *(const bf16x8*)(vp + (size_t)lane * QKV_LD + d0);
    bf16x8 vr1 = *(const bf16x8*)(vp + (size_t)lane * QKV_LD + d0 + 32);
    {
        #pragma unroll
        for (int ii = 0; ii < 2; ++ii) {
            const int row = wave * 16 + ii * 8 + (lane >> 3);
            const int o   = (lane & 7) ^ (lane >> 3);
            gl_lds16(kp + (size_t)row * QKV_LD + o * 8, &Ks[0][(wave * 2 + ii) * 512]);
        }
        #pragma unroll
        for (int ii = 0; ii < 8; ++ii) {
            const int po = ((lane >> 3) ^ ii) * 8 + (lane & 7);
            Vt[0][((d0 + ii) << 6) + po]      = (unsigned short)vr0[ii];
            Vt[0][((d0 + 32 + ii) << 6) + po] = (unsigned short)vr1[ii];
        }
        if (nB > 1) {
            vr0 = *(const bf16x8*)(vp + (size_t)(64 + lane) * QKV_LD + d0);
            vr1 = *(const bf16x8*)(vp + (size_t)(64 + lane) * QKV_LD + d0 + 32);
        }
    }
    __syncthreads();

    f32x4 oA[4], oB[4], lA, lB;
    #pragma unroll
    for (int t = 0; t < 4; ++t) {
        oA[t] = (f32x4){0.f, 0.f, 0.f, 0.f};
        oB[t] = (f32x4){0.f, 0.f, 0.f, 0.f};
    }
    lA = (f32x4){0.f, 0.f, 0.f, 0.f};
    lB = (f32x4){0.f, 0.f, 0.f, 0.f};

    for (int kc = 0; kc < nB; ++kc) {
        const int cur = kc & 1;
        unsigned short* ksc = &Ks[cur][0];
        unsigned short* vtc = &Vt[cur][0];

        if (kc + 1 < nB) {
            const int key1 = (kc + 1) * 64;
            #pragma unroll
            for (int ii = 0; ii < 2; ++ii) {
                const int row = wave * 16 + ii * 8 + (lane >> 3);
                const int o   = (lane & 7) ^ (lane >> 3);
                gl_lds16(kp + (size_t)(key1 + row) * QKV_LD + o * 8,
                         &Ks[cur ^ 1][(wave * 2 + ii) * 512]);
            }
            unsigned short* vtn = &Vt[cur ^ 1][0];
            #pragma unroll
            for (int ii = 0; ii < 8; ++ii) {
                const int po = ((lane >> 3) ^ ii) * 8 + (lane & 7);
                vtn[((d0 + ii) << 6) + po]      = (unsigned short)vr0[ii];
                vtn[((d0 + 32 + ii) << 6) + po] = (unsigned short)vr1[ii];
            }
        }
        if (kc + 2 < nB) {
            const int key2 = (kc + 2) * 64;
            vr0 = *(const bf16x8*)(vp + (size_t)(key2 + lane) * QKV_LD + d0);
            vr1 = *(const bf16x8*)(vp + (size_t)(key2 + lane) * QKV_LD + d0 + 32);
        }

        const int key0 = kc * 64;
        bf16x8 kf[4][2];
        #pragma unroll
        for (int t = 0; t < 4; ++t)
            #pragma unroll
            for (int i = 0; i < 2; ++i)
                kf[t][i] = *(const bf16x8*)
                    &ksc[((t * 16 + low) << 6) + (((quad + 4 * i) ^ (low & 7)) << 3)];

        if (kc < nA) {
            if (kc == nA - 1)
                tile_step<true >(kf, qfA0, qfA1, qmyA - key0 - quad * 4, quad, low, psA);
            else
                tile_step<false>(kf, qfA0, qfA1, 0, quad, low, psA);
        }
        if (kc == nB - 1)
            tile_step<true >(kf, qfB0, qfB1, qmyB - key0 - quad * 4, quad, low, psB);
        else
            tile_step<false>(kf, qfB0, qfB1, 0, quad, low, psB);

        asm volatile("" ::: "memory");   // per-wave Ps: program order + fence

        bf16x8 vf[4][2];
        #pragma unroll
        for (int t = 0; t < 4; ++t)
            #pragma unroll
            for (int i = 0; i < 2; ++i)
                vf[t][i] = *(const bf16x8*)
                    &vtc[((t * 16 + low) << 6) + (((quad + 4 * i) ^ (low & 7)) << 3)];

        if (kc < nA) pv_step(vf, psA, quad, low, oA, lA, ones);
        pv_step(vf, psB, quad, low, oB, lB, ones);
        __syncthreads();
    }

    #pragma unroll
    for (int r = 0; r < 4; ++r) {
        const float rlA = 1.f / lA[r];
        const int qrow = qA0 + wave * 16 + quad * 4 + r;
        unsigned short* yp = y + (size_t)(b * SEQ_T + qrow) * N_EMBD + h * 64 + low;
        #pragma unroll
        for (int t = 0; t < 4; ++t) yp[16 * t] = f2bf(oA[t][r] * rlA);
    }
    #pragma unroll
    for (int r = 0; r < 4; ++r) {
        const float rlB = 1.f / lB[r];
        const int qrow = qB0 + wave * 16 + quad * 4 + r;
        unsigned short* yp = y + (size_t)(b * SEQ_T + qrow) * N_EMBD + h * 64 + low;
        #pragma unroll
        for (int t = 0; t < 4; ++t) yp[16 * t] = f2bf(oB[t][r] * rlB);
    }
}

// ---------------------------------------------------------------------------
extern "C" void kernel_launch(void* const* d_in, const int* in_sizes, int n_in,
                              void* d_out, int out_size, void* d_ws, size_t ws_size,
                              hipStream_t stream)
{
    const float* x      = (const float*)d_in[0];
    const float* attn_w = (const float*)d_in[1];   // [512][1536]
    const float* attn_b = (const float*)d_in[2];
    const float* proj_w = (const float*)d_in[3];   // [512][512]
    const float* proj_b = (const float*)d_in[4];
    float*       out    = (float*)d_out;

    char* ws = (char*)d_ws;
    unsigned short* qkv_bf = (unsigned short*)(ws);                      // 25.2 MB
    unsigned short* y_bf   = (unsigned short*)(ws + 25165824);           //  8.4 MB
    unsigned short* w1t    = (unsigned short*)(ws + 33554432);           //  1.6 MB
    unsigned short* w2t    = (unsigned short*)(ws + 35127296);           //  0.5 MB

    prep<<<1024, 256, 0, stream>>>(attn_w, w1t, proj_w, w2t);

    // qkv = x(fp32, converted in-staging) @ w1t^T + b
    gemm_mfma<128, 128, true, true><<<dim3(12, 64), 256, 0, stream>>>(
        x, w1t, attn_b, qkv_bf, QKV_LD, N_EMBD);

    attn_mfma<<<dim3(16, BATCH * N_HEAD), 256, 0, stream>>>(qkv_bf, y_bf);

    gemm_mfma<64, 128, false, false><<<dim3(4, 128), 256, 0, stream>>>(
        y_bf, w2t, proj_b, out, N_EMBD, N_EMBD);
}

// Round 9
// 152.227 us; speedup vs baseline: 1.1275x; 1.0489x over previous
//
#include <hip/hip_runtime.h>
#include <math.h>

#define N_EMBD 512
#define N_HEAD 8
#define SEQ_T  2048
#define BATCH  4
#define QKV_LD 1536

typedef __attribute__((ext_vector_type(8))) short bf16x8;  // 8 bf16 (4 VGPRs)
typedef __attribute__((ext_vector_type(4))) float f32x4;

#define CL 0.18033688f   // 0.125 * log2(e)

__device__ __forceinline__ unsigned short f2bf(float f) {
    union { float f; unsigned int u; } x; x.f = f;
    return (unsigned short)((x.u + 0x7FFFu + ((x.u >> 16) & 1u)) >> 16);  // RNE
}
// pack trunc-bf16(a) | trunc-bf16(b)<<16 in ONE v_perm
__device__ __forceinline__ unsigned pack_trunc(float a, float b) {
    union { float f; unsigned u; } x, y; x.f = a; y.f = b;
    return __builtin_amdgcn_perm(y.u, x.u, 0x07060302u);
}
// bf16x8 * scalar (unpack, mul, RNE repack) — once per block for Q
__device__ __forceinline__ bf16x8 scale_frag(bf16x8 v, float c) {
    bf16x8 r;
    #pragma unroll
    for (int i = 0; i < 8; ++i) {
        union { unsigned u; float f; } x;
        x.u = ((unsigned)(unsigned short)v[i]) << 16;
        r[i] = (short)f2bf(x.f * c);
    }
    return r;
}

// async global->LDS, 16B per lane; dest = wave-uniform base + lane*16
__device__ __forceinline__ void gl_lds16(const void* g, void* s) {
    __builtin_amdgcn_global_load_lds(
        (const __attribute__((address_space(1))) void*)g,
        (__attribute__((address_space(3))) void*)s, 16, 0, 0);
}

// ---------------------------------------------------------------------------
// prep (weights only): [0,768) transpose attn_w ; [768,1024) proj_w
// ---------------------------------------------------------------------------
__global__ __launch_bounds__(256) void prep(
    const float* __restrict__ w1, unsigned short* __restrict__ w1t,
    const float* __restrict__ w2, unsigned short* __restrict__ w2t)
{
    __shared__ float t[32][33];
    const int bx = blockIdx.x, tid = threadIdx.x;
    const float* W; unsigned short* Wt; int N, tt, nb;
    if (bx < 768) { tt = bx;       W = w1; Wt = w1t; N = 1536; nb = 48; }
    else          { tt = bx - 768; W = w2; Wt = w2t; N = 512;  nb = 16; }
    const int n0 = (tt % nb) * 32, k0 = (tt / nb) * 32;
    const int tx = tid & 31, ty = tid >> 5;
    #pragma unroll
    for (int i = 0; i < 4; ++i)
        t[ty + i * 8][tx] = W[(size_t)(k0 + ty + i * 8) * N + n0 + tx];
    __syncthreads();
    #pragma unroll
    for (int i = 0; i < 4; ++i)
        Wt[(size_t)(n0 + ty + i * 8) * 512 + k0 + tx] = f2bf(t[tx][ty + i * 8]);
}

// ---------------------------------------------------------------------------
// MFMA GEMM v5: BK=64, SINGLE LDS buffer, reg-staged prefetch with a full
// iteration of slack (R8-proven), 8 K-iters for K=512 (half the barriers of
// BK=32), 32 MFMA between barrier pairs. 8-oct XOR swizzle:
//   stage: thread (m, q) writes phys oct q^(m&7); read: po=(h*4+quad)^(low&7)
//   -> uniform 8 lanes per 4-bank group on both sides (balanced = free).
// ---------------------------------------------------------------------------
template <int BM, int BN, bool CVT_A, bool BF16_OUT>
__global__ __launch_bounds__(256) void gemm_mfma(
    const void* __restrict__ Asrc,              // fp32 [M][K] if CVT_A else bf16
    const unsigned short* __restrict__ Bt,      // bf16 [N][K]
    const float* __restrict__ bias,
    void* __restrict__ C, int N, int K)
{
    constexpr int WMT = BM / 32, WNT = BN / 32;
    constexpr int SA = BM * 8 / 256, SB = BN * 8 / 256;   // octs per thread
    __shared__ unsigned short As[BM * 64];
    __shared__ unsigned short Bs[BN * 64];

    const int tid  = threadIdx.x;
    const int wave = tid >> 6, lane = tid & 63;
    const int low  = lane & 15, quad = lane >> 4;
    const int wm   = (wave & 1) * (BM / 2), wn = (wave >> 1) * (BN / 2);
    const int row0 = blockIdx.y * BM, col0 = blockIdx.x * BN;

    size_t a_src[SA]; int a_dst[SA];
    #pragma unroll
    for (int s = 0; s < SA; ++s) {
        const int p = tid + 256 * s;
        const int m = p >> 3, q = p & 7;
        a_src[s] = (size_t)(row0 + m) * K + q * 8;
        a_dst[s] = m * 64 + (q ^ (m & 7)) * 8;
    }
    size_t b_src[SB]; int b_dst[SB];
    #pragma unroll
    for (int s = 0; s < SB; ++s) {
        const int p = tid + 256 * s;
        const int m = p >> 3, q = p & 7;
        b_src[s] = (size_t)(col0 + m) * K + q * 8;
        b_dst[s] = m * 64 + (q ^ (m & 7)) * 8;
    }

    f32x4 acc[WMT][WNT];
    #pragma unroll
    for (int i = 0; i < WMT; ++i)
        #pragma unroll
        for (int j = 0; j < WNT; ++j) acc[i][j] = (f32x4){0.f, 0.f, 0.f, 0.f};

    bf16x8 ar[SA], br[SB];
    const float*          af32 = (const float*)Asrc;
    const unsigned short* a16  = (const unsigned short*)Asrc;

    #pragma unroll
    for (int s = 0; s < SA; ++s) {
        if (CVT_A) {
            const float4 f0 = *(const float4*)(af32 + a_src[s]);
            const float4 f1 = *(const float4*)(af32 + a_src[s] + 4);
            union { uint4 v; bf16x8 h; } u;
            u.v.x = pack_trunc(f0.x, f0.y); u.v.y = pack_trunc(f0.z, f0.w);
            u.v.z = pack_trunc(f1.x, f1.y); u.v.w = pack_trunc(f1.z, f1.w);
            ar[s] = u.h;
        } else {
            ar[s] = *(const bf16x8*)(a16 + a_src[s]);
        }
    }
    #pragma unroll
    for (int s = 0; s < SB; ++s) br[s] = *(const bf16x8*)(Bt + b_src[s]);

    const int NIT = K >> 6;
    for (int it = 0; it < NIT; ++it) {
        __syncthreads();   // prev iter's frag reads done (buffer free)
        #pragma unroll
        for (int s = 0; s < SA; ++s) *(bf16x8*)&As[a_dst[s]] = ar[s];
        #pragma unroll
        for (int s = 0; s < SB; ++s) *(bf16x8*)&Bs[b_dst[s]] = br[s];
        __syncthreads();   // staged tile visible (waits only LDS writes)

        if (it + 1 < NIT) {   // global loads for it+1: full iter of slack
            const int ko = (it + 1) * 64;
            #pragma unroll
            for (int s = 0; s < SA; ++s) {
                if (CVT_A) {
                    const float4 f0 = *(const float4*)(af32 + a_src[s] + ko);
                    const float4 f1 = *(const float4*)(af32 + a_src[s] + ko + 4);
                    union { uint4 v; bf16x8 h; } u;
                    u.v.x = pack_trunc(f0.x, f0.y); u.v.y = pack_trunc(f0.z, f0.w);
                    u.v.z = pack_trunc(f1.x, f1.y); u.v.w = pack_trunc(f1.z, f1.w);
                    ar[s] = u.h;
                } else {
                    ar[s] = *(const bf16x8*)(a16 + a_src[s] + ko);
                }
            }
            #pragma unroll
            for (int s = 0; s < SB; ++s) br[s] = *(const bf16x8*)(Bt + b_src[s] + ko);
        }

        #pragma unroll
        for (int h = 0; h < 2; ++h) {     // two k-halves of the 64-deep tile
            bf16x8 af[WMT], bfr[WNT];
            #pragma unroll
            for (int t = 0; t < WMT; ++t)
                af[t] = *(const bf16x8*)
                    &As[(wm + t * 16 + low) * 64 + (((h * 4 + quad) ^ (low & 7)) * 8)];
            #pragma unroll
            for (int t = 0; t < WNT; ++t)
                bfr[t] = *(const bf16x8*)
                    &Bs[(wn + t * 16 + low) * 64 + (((h * 4 + quad) ^ (low & 7)) * 8)];
            #pragma unroll
            for (int i = 0; i < WMT; ++i)
                #pragma unroll
                for (int j = 0; j < WNT; ++j)
                    acc[i][j] = __builtin_amdgcn_mfma_f32_16x16x32_bf16(
                        af[i], bfr[j], acc[i][j], 0, 0, 0);
        }
    }

    float bv[WNT];
    #pragma unroll
    for (int j = 0; j < WNT; ++j) bv[j] = bias[col0 + wn + j * 16 + low];
    #pragma unroll
    for (int i = 0; i < WMT; ++i)
        #pragma unroll
        for (int r = 0; r < 4; ++r) {
            const size_t row = row0 + wm + i * 16 + quad * 4 + r;
            #pragma unroll
            for (int j = 0; j < WNT; ++j) {
                const int col = col0 + wn + j * 16 + low;
                const float v = acc[i][j][r] + bv[j];
                if (BF16_OUT)
                    ((unsigned short*)C)[row * N + col] = f2bf(v);
                else
                    ((float*)C)[row * N + col] = v;
            }
        }
}

// ---------------------------------------------------------------------------
// attention (R6/R8-proven body; only change: 1D grid with bh = id%32 so all
// 16 pa-blocks of one bh map to one XCD under %8 round-robin dispatch ->
// K/V stays in that XCD's L2 (4 bh x 512 KB = 2 MB < 4 MB)).
// ---------------------------------------------------------------------------
template <bool MASK>
__device__ __forceinline__ void tile_step(
    const bf16x8 kf[4][2], const bf16x8 qf0, const bf16x8 qf1,
    int thr, int quad, int low, unsigned short* ps)
{
    f32x4 s[4];
    #pragma unroll
    for (int st = 0; st < 4; ++st) {
        f32x4 a = (f32x4){0.f, 0.f, 0.f, 0.f};
        a = __builtin_amdgcn_mfma_f32_16x16x32_bf16(kf[st][0], qf0, a, 0, 0, 0);
        a = __builtin_amdgcn_mfma_f32_16x16x32_bf16(kf[st][1], qf1, a, 0, 0, 0);
        s[st] = a;
    }
    #pragma unroll
    for (int st = 0; st < 4; ++st) {
        float p[4];
        #pragma unroll
        for (int r = 0; r < 4; ++r) {
            float v = s[st][r];
            if (MASK) v = (st * 16 + r <= thr) ? v : -1e30f;  // exp2 -> 0
            p[r] = __builtin_amdgcn_exp2f(v);
        }
        uint2 pk;
        pk.x = pack_trunc(p[0], p[1]);
        pk.y = pack_trunc(p[2], p[3]);
        *(uint2*)&ps[low * 72 + st * 16 + quad * 4] = pk;
    }
}

__device__ __forceinline__ void pv_step(
    const bf16x8 vf[4][2], const unsigned short* ps, int quad, int low,
    f32x4* o, f32x4& lacc, const bf16x8 ones)
{
    const bf16x8 p0 = *(const bf16x8*)&ps[low * 72 + quad * 8];
    const bf16x8 p1 = *(const bf16x8*)&ps[low * 72 + quad * 8 + 32];
    #pragma unroll
    for (int t = 0; t < 4; ++t) {
        o[t] = __builtin_amdgcn_mfma_f32_16x16x32_bf16(p0, vf[t][0], o[t], 0, 0, 0);
        o[t] = __builtin_amdgcn_mfma_f32_16x16x32_bf16(p1, vf[t][1], o[t], 0, 0, 0);
    }
    lacc = __builtin_amdgcn_mfma_f32_16x16x32_bf16(p0, ones, lacc, 0, 0, 0);
    lacc = __builtin_amdgcn_mfma_f32_16x16x32_bf16(p1, ones, lacc, 0, 0, 0);
}

__global__ __launch_bounds__(256) void attn_mfma(
    const unsigned short* __restrict__ qkv,   // bf16 [8192][1536]
    unsigned short* __restrict__ y)           // bf16 [8192][512]
{
    const int bh  = blockIdx.x & 31;          // same-bh blocks -> same XCD
    const int pa  = blockIdx.x >> 5;          // 0..15
    const int b   = bh >> 3, h = bh & 7;
    const int qA0 = pa * 64;
    const int qB0 = (31 - pa) * 64;
    const int nA  = pa + 1, nB = 32 - pa;
    const int tid = threadIdx.x;
    const int wave = tid >> 6, lane = tid & 63;
    const int low  = lane & 15, quad = lane >> 4;

    __shared__ unsigned short Ks[2][64 * 64];
    __shared__ unsigned short Vt[2][64 * 64];
    __shared__ unsigned short PsA[4][16 * 72];
    __shared__ unsigned short PsB[4][16 * 72];

    const size_t base = (size_t)b * SEQ_T * QKV_LD + h * 64;
    const unsigned short* qp = qkv + base;
    const unsigned short* kp = qkv + base + 512;
    const unsigned short* vp = qkv + base + 1024;

    const int qmyA = qA0 + wave * 16 + low;
    const int qmyB = qB0 + wave * 16 + low;

    const bf16x8 qfA0 = scale_frag(*(const bf16x8*)(qp + (size_t)qmyA * QKV_LD + quad * 8), CL);
    const bf16x8 qfA1 = scale_frag(*(const bf16x8*)(qp + (size_t)qmyA * QKV_LD + quad * 8 + 32), CL);
    const bf16x8 qfB0 = scale_frag(*(const bf16x8*)(qp + (size_t)qmyB * QKV_LD + quad * 8), CL);
    const bf16x8 qfB1 = scale_frag(*(const bf16x8*)(qp + (size_t)qmyB * QKV_LD + quad * 8 + 32), CL);

    bf16x8 ones;
    #pragma unroll
    for (int i = 0; i < 8; ++i) ones[i] = (short)0x3F80;   // bf16 1.0

    const int d0 = wave * 8;
    unsigned short* psA = &PsA[wave][0];
    unsigned short* psB = &PsB[wave][0];

    bf16x8 vr0 = *(const bf16x8*)(vp + (size_t)lane * QKV_LD + d0);
    bf16x8 vr1 = *(const bf16x8*)(vp + (size_t)lane * QKV_LD + d0 + 32);
    {
        #pragma unroll
        for (int ii = 0; ii < 2; ++ii) {
            const int row = wave * 16 + ii * 8 + (lane >> 3);
            const int o   = (lane & 7) ^ (lane >> 3);
            gl_lds16(kp + (size_t)row * QKV_LD + o * 8, &Ks[0][(wave * 2 + ii) * 512]);
        }
        #pragma unroll
        for (int ii = 0; ii < 8; ++ii) {
            const int po = ((lane >> 3) ^ ii) * 8 + (lane & 7);
            Vt[0][((d0 + ii) << 6) + po]      = (unsigned short)vr0[ii];
            Vt[0][((d0 + 32 + ii) << 6) + po] = (unsigned short)vr1[ii];
        }
        if (nB > 1) {
            vr0 = *(const bf16x8*)(vp + (size_t)(64 + lane) * QKV_LD + d0);
            vr1 = *(const bf16x8*)(vp + (size_t)(64 + lane) * QKV_LD + d0 + 32);
        }
    }
    __syncthreads();

    f32x4 oA[4], oB[4], lA, lB;
    #pragma unroll
    for (int t = 0; t < 4; ++t) {
        oA[t] = (f32x4){0.f, 0.f, 0.f, 0.f};
        oB[t] = (f32x4){0.f, 0.f, 0.f, 0.f};
    }
    lA = (f32x4){0.f, 0.f, 0.f, 0.f};
    lB = (f32x4){0.f, 0.f, 0.f, 0.f};

    for (int kc = 0; kc < nB; ++kc) {
        const int cur = kc & 1;
        unsigned short* ksc = &Ks[cur][0];
        unsigned short* vtc = &Vt[cur][0];

        if (kc + 1 < nB) {
            const int key1 = (kc + 1) * 64;
            #pragma unroll
            for (int ii = 0; ii < 2; ++ii) {
                const int row = wave * 16 + ii * 8 + (lane >> 3);
                const int o   = (lane & 7) ^ (lane >> 3);
                gl_lds16(kp + (size_t)(key1 + row) * QKV_LD + o * 8,
                         &Ks[cur ^ 1][(wave * 2 + ii) * 512]);
            }
            unsigned short* vtn = &Vt[cur ^ 1][0];
            #pragma unroll
            for (int ii = 0; ii < 8; ++ii) {
                const int po = ((lane >> 3) ^ ii) * 8 + (lane & 7);
                vtn[((d0 + ii) << 6) + po]      = (unsigned short)vr0[ii];
                vtn[((d0 + 32 + ii) << 6) + po] = (unsigned short)vr1[ii];
            }
        }
        if (kc + 2 < nB) {
            const int key2 = (kc + 2) * 64;
            vr0 = *(const bf16x8*)(vp + (size_t)(key2 + lane) * QKV_LD + d0);
            vr1 = *(const bf16x8*)(vp + (size_t)(key2 + lane) * QKV_LD + d0 + 32);
        }

        const int key0 = kc * 64;
        bf16x8 kf[4][2];
        #pragma unroll
        for (int t = 0; t < 4; ++t)
            #pragma unroll
            for (int i = 0; i < 2; ++i)
                kf[t][i] = *(const bf16x8*)
                    &ksc[((t * 16 + low) << 6) + (((quad + 4 * i) ^ (low & 7)) << 3)];

        if (kc < nA) {
            if (kc == nA - 1)
                tile_step<true >(kf, qfA0, qfA1, qmyA - key0 - quad * 4, quad, low, psA);
            else
                tile_step<false>(kf, qfA0, qfA1, 0, quad, low, psA);
        }
        if (kc == nB - 1)
            tile_step<true >(kf, qfB0, qfB1, qmyB - key0 - quad * 4, quad, low, psB);
        else
            tile_step<false>(kf, qfB0, qfB1, 0, quad, low, psB);

        asm volatile("" ::: "memory");   // per-wave Ps: program order + fence

        bf16x8 vf[4][2];
        #pragma unroll
        for (int t = 0; t < 4; ++t)
            #pragma unroll
            for (int i = 0; i < 2; ++i)
                vf[t][i] = *(const bf16x8*)
                    &vtc[((t * 16 + low) << 6) + (((quad + 4 * i) ^ (low & 7)) << 3)];

        if (kc < nA) pv_step(vf, psA, quad, low, oA, lA, ones);
        pv_step(vf, psB, quad, low, oB, lB, ones);
        __syncthreads();
    }

    #pragma unroll
    for (int r = 0; r < 4; ++r) {
        const float rlA = 1.f / lA[r];
        const int qrow = qA0 + wave * 16 + quad * 4 + r;
        unsigned short* yp = y + (size_t)(b * SEQ_T + qrow) * N_EMBD + h * 64 + low;
        #pragma unroll
        for (int t = 0; t < 4; ++t) yp[16 * t] = f2bf(oA[t][r] * rlA);
    }
    #pragma unroll
    for (int r = 0; r < 4; ++r) {
        const float rlB = 1.f / lB[r];
        const int qrow = qB0 + wave * 16 + quad * 4 + r;
        unsigned short* yp = y + (size_t)(b * SEQ_T + qrow) * N_EMBD + h * 64 + low;
        #pragma unroll
        for (int t = 0; t < 4; ++t) yp[16 * t] = f2bf(oB[t][r] * rlB);
    }
}

// ---------------------------------------------------------------------------
extern "C" void kernel_launch(void* const* d_in, const int* in_sizes, int n_in,
                              void* d_out, int out_size, void* d_ws, size_t ws_size,
                              hipStream_t stream)
{
    const float* x      = (const float*)d_in[0];
    const float* attn_w = (const float*)d_in[1];   // [512][1536]
    const float* attn_b = (const float*)d_in[2];
    const float* proj_w = (const float*)d_in[3];   // [512][512]
    const float* proj_b = (const float*)d_in[4];
    float*       out    = (float*)d_out;

    char* ws = (char*)d_ws;
    unsigned short* qkv_bf = (unsigned short*)(ws);                      // 25.2 MB
    unsigned short* y_bf   = (unsigned short*)(ws + 25165824);           //  8.4 MB
    unsigned short* w1t    = (unsigned short*)(ws + 33554432);           //  1.6 MB
    unsigned short* w2t    = (unsigned short*)(ws + 35127296);           //  0.5 MB

    prep<<<1024, 256, 0, stream>>>(attn_w, w1t, proj_w, w2t);

    // qkv = x(fp32, converted in-staging) @ w1t^T + b
    gemm_mfma<128, 128, true, true><<<dim3(12, 64), 256, 0, stream>>>(
        x, w1t, attn_b, qkv_bf, QKV_LD, N_EMBD);

    attn_mfma<<<dim3(512), 256, 0, stream>>>(qkv_bf, y_bf);

    gemm_mfma<64, 128, false, false><<<dim3(4, 128), 256, 0, stream>>>(
        y_bf, w2t, proj_b, out, N_EMBD, N_EMBD);
}

// Round 10
// 146.371 us; speedup vs baseline: 1.1726x; 1.0400x over previous
//
#include <hip/hip_runtime.h>
#include <math.h>

#define N_EMBD 512
#define N_HEAD 8
#define SEQ_T  2048
#define BATCH  4
#define QKV_LD 1536

typedef __attribute__((ext_vector_type(8))) short bf16x8;  // 8 bf16 (4 VGPRs)
typedef __attribute__((ext_vector_type(4))) float f32x4;

#define CL 0.18033688f   // 0.125 * log2(e)

__device__ __forceinline__ unsigned short f2bf(float f) {
    union { float f; unsigned int u; } x; x.f = f;
    return (unsigned short)((x.u + 0x7FFFu + ((x.u >> 16) & 1u)) >> 16);  // RNE
}
// pack trunc-bf16(a) | trunc-bf16(b)<<16 in ONE v_perm
__device__ __forceinline__ unsigned pack_trunc(float a, float b) {
    union { float f; unsigned u; } x, y; x.f = a; y.f = b;
    return __builtin_amdgcn_perm(y.u, x.u, 0x07060302u);
}
// bf16x8 * scalar (unpack, mul, RNE repack) — once per block for Q
__device__ __forceinline__ bf16x8 scale_frag(bf16x8 v, float c) {
    bf16x8 r;
    #pragma unroll
    for (int i = 0; i < 8; ++i) {
        union { unsigned u; float f; } x;
        x.u = ((unsigned)(unsigned short)v[i]) << 16;
        r[i] = (short)f2bf(x.f * c);
    }
    return r;
}

// async global->LDS, 16B per lane; dest = wave-uniform base + lane*16
__device__ __forceinline__ void gl_lds16(const void* g, void* s) {
    __builtin_amdgcn_global_load_lds(
        (const __attribute__((address_space(1))) void*)g,
        (__attribute__((address_space(3))) void*)s, 16, 0, 0);
}

// ---------------------------------------------------------------------------
// prep (weights only): [0,768) transpose attn_w ; [768,1024) proj_w
// ---------------------------------------------------------------------------
__global__ __launch_bounds__(256) void prep(
    const float* __restrict__ w1, unsigned short* __restrict__ w1t,
    const float* __restrict__ w2, unsigned short* __restrict__ w2t)
{
    __shared__ float t[32][33];
    const int bx = blockIdx.x, tid = threadIdx.x;
    const float* W; unsigned short* Wt; int N, tt, nb;
    if (bx < 768) { tt = bx;       W = w1; Wt = w1t; N = 1536; nb = 48; }
    else          { tt = bx - 768; W = w2; Wt = w2t; N = 512;  nb = 16; }
    const int n0 = (tt % nb) * 32, k0 = (tt / nb) * 32;
    const int tx = tid & 31, ty = tid >> 5;
    #pragma unroll
    for (int i = 0; i < 4; ++i)
        t[ty + i * 8][tx] = W[(size_t)(k0 + ty + i * 8) * N + n0 + tx];
    __syncthreads();
    #pragma unroll
    for (int i = 0; i < 4; ++i)
        Wt[(size_t)(n0 + ty + i * 8) * 512 + k0 + tx] = f2bf(t[tx][ty + i * 8]);
}

// ---------------------------------------------------------------------------
// MFMA GEMM v6 = R9 body + XCD-local 1D grid (R9-attn-proven %8 heuristic):
//   xcd = id&7; each XCD owns xcdRows row-slabs x ALL colTiles columns, so
//   its A-slab + full weight matrix stay hot in that XCD's 4 MB L2
//   (gemm1: 2 MB x + 1.5 MB w; gemm2: 1 MB y + 0.5 MB w). All of an XCD's
//   blocks are co-resident (3/CU x 32 CU >= blocks/XCD).
// Pure block-id permutation -> bit-identical results to R9.
// ---------------------------------------------------------------------------
template <int BM, int BN, bool CVT_A, bool BF16_OUT>
__global__ __launch_bounds__(256) void gemm_mfma(
    const void* __restrict__ Asrc,              // fp32 [M][K] if CVT_A else bf16
    const unsigned short* __restrict__ Bt,      // bf16 [N][K]
    const float* __restrict__ bias,
    void* __restrict__ C, int N, int K,
    int xcdRows)                                // row-slabs per XCD
{
    constexpr int WMT = BM / 32, WNT = BN / 32;
    constexpr int SA = BM * 8 / 256, SB = BN * 8 / 256;   // octs per thread
    __shared__ unsigned short As[BM * 64];
    __shared__ unsigned short Bs[BN * 64];

    const int tid  = threadIdx.x;
    const int wave = tid >> 6, lane = tid & 63;
    const int low  = lane & 15, quad = lane >> 4;
    const int wm   = (wave & 1) * (BM / 2), wn = (wave >> 1) * (BN / 2);

    // XCD-local tile mapping
    const int xcd    = blockIdx.x & 7;
    const int within = blockIdx.x >> 3;
    const int rowBlk = xcd * xcdRows + (within % xcdRows);
    const int colBlk = within / xcdRows;
    const int row0 = rowBlk * BM, col0 = colBlk * BN;

    size_t a_src[SA]; int a_dst[SA];
    #pragma unroll
    for (int s = 0; s < SA; ++s) {
        const int p = tid + 256 * s;
        const int m = p >> 3, q = p & 7;
        a_src[s] = (size_t)(row0 + m) * K + q * 8;
        a_dst[s] = m * 64 + (q ^ (m & 7)) * 8;
    }
    size_t b_src[SB]; int b_dst[SB];
    #pragma unroll
    for (int s = 0; s < SB; ++s) {
        const int p = tid + 256 * s;
        const int m = p >> 3, q = p & 7;
        b_src[s] = (size_t)(col0 + m) * K + q * 8;
        b_dst[s] = m * 64 + (q ^ (m & 7)) * 8;
    }

    f32x4 acc[WMT][WNT];
    #pragma unroll
    for (int i = 0; i < WMT; ++i)
        #pragma unroll
        for (int j = 0; j < WNT; ++j) acc[i][j] = (f32x4){0.f, 0.f, 0.f, 0.f};

    bf16x8 ar[SA], br[SB];
    const float*          af32 = (const float*)Asrc;
    const unsigned short* a16  = (const unsigned short*)Asrc;

    #pragma unroll
    for (int s = 0; s < SA; ++s) {
        if (CVT_A) {
            const float4 f0 = *(const float4*)(af32 + a_src[s]);
            const float4 f1 = *(const float4*)(af32 + a_src[s] + 4);
            union { uint4 v; bf16x8 h; } u;
            u.v.x = pack_trunc(f0.x, f0.y); u.v.y = pack_trunc(f0.z, f0.w);
            u.v.z = pack_trunc(f1.x, f1.y); u.v.w = pack_trunc(f1.z, f1.w);
            ar[s] = u.h;
        } else {
            ar[s] = *(const bf16x8*)(a16 + a_src[s]);
        }
    }
    #pragma unroll
    for (int s = 0; s < SB; ++s) br[s] = *(const bf16x8*)(Bt + b_src[s]);

    const int NIT = K >> 6;
    for (int it = 0; it < NIT; ++it) {
        __syncthreads();   // prev iter's frag reads done (buffer free)
        #pragma unroll
        for (int s = 0; s < SA; ++s) *(bf16x8*)&As[a_dst[s]] = ar[s];
        #pragma unroll
        for (int s = 0; s < SB; ++s) *(bf16x8*)&Bs[b_dst[s]] = br[s];
        __syncthreads();   // staged tile visible (waits only LDS writes)

        if (it + 1 < NIT) {   // global loads for it+1: full iter of slack
            const int ko = (it + 1) * 64;
            #pragma unroll
            for (int s = 0; s < SA; ++s) {
                if (CVT_A) {
                    const float4 f0 = *(const float4*)(af32 + a_src[s] + ko);
                    const float4 f1 = *(const float4*)(af32 + a_src[s] + ko + 4);
                    union { uint4 v; bf16x8 h; } u;
                    u.v.x = pack_trunc(f0.x, f0.y); u.v.y = pack_trunc(f0.z, f0.w);
                    u.v.z = pack_trunc(f1.x, f1.y); u.v.w = pack_trunc(f1.z, f1.w);
                    ar[s] = u.h;
                } else {
                    ar[s] = *(const bf16x8*)(a16 + a_src[s] + ko);
                }
            }
            #pragma unroll
            for (int s = 0; s < SB; ++s) br[s] = *(const bf16x8*)(Bt + b_src[s] + ko);
        }

        #pragma unroll
        for (int h = 0; h < 2; ++h) {     // two k-halves of the 64-deep tile
            bf16x8 af[WMT], bfr[WNT];
            #pragma unroll
            for (int t = 0; t < WMT; ++t)
                af[t] = *(const bf16x8*)
                    &As[(wm + t * 16 + low) * 64 + (((h * 4 + quad) ^ (low & 7)) * 8)];
            #pragma unroll
            for (int t = 0; t < WNT; ++t)
                bfr[t] = *(const bf16x8*)
                    &Bs[(wn + t * 16 + low) * 64 + (((h * 4 + quad) ^ (low & 7)) * 8)];
            #pragma unroll
            for (int i = 0; i < WMT; ++i)
                #pragma unroll
                for (int j = 0; j < WNT; ++j)
                    acc[i][j] = __builtin_amdgcn_mfma_f32_16x16x32_bf16(
                        af[i], bfr[j], acc[i][j], 0, 0, 0);
        }
    }

    float bv[WNT];
    #pragma unroll
    for (int j = 0; j < WNT; ++j) bv[j] = bias[col0 + wn + j * 16 + low];
    #pragma unroll
    for (int i = 0; i < WMT; ++i)
        #pragma unroll
        for (int r = 0; r < 4; ++r) {
            const size_t row = row0 + wm + i * 16 + quad * 4 + r;
            #pragma unroll
            for (int j = 0; j < WNT; ++j) {
                const int col = col0 + wn + j * 16 + low;
                const float v = acc[i][j][r] + bv[j];
                if (BF16_OUT)
                    ((unsigned short*)C)[row * N + col] = f2bf(v);
                else
                    ((float*)C)[row * N + col] = v;
            }
        }
}

// ---------------------------------------------------------------------------
// attention (R9 kernel, verbatim — 45.6 us, FETCH 12.4 MB proven)
// ---------------------------------------------------------------------------
template <bool MASK>
__device__ __forceinline__ void tile_step(
    const bf16x8 kf[4][2], const bf16x8 qf0, const bf16x8 qf1,
    int thr, int quad, int low, unsigned short* ps)
{
    f32x4 s[4];
    #pragma unroll
    for (int st = 0; st < 4; ++st) {
        f32x4 a = (f32x4){0.f, 0.f, 0.f, 0.f};
        a = __builtin_amdgcn_mfma_f32_16x16x32_bf16(kf[st][0], qf0, a, 0, 0, 0);
        a = __builtin_amdgcn_mfma_f32_16x16x32_bf16(kf[st][1], qf1, a, 0, 0, 0);
        s[st] = a;
    }
    #pragma unroll
    for (int st = 0; st < 4; ++st) {
        float p[4];
        #pragma unroll
        for (int r = 0; r < 4; ++r) {
            float v = s[st][r];
            if (MASK) v = (st * 16 + r <= thr) ? v : -1e30f;  // exp2 -> 0
            p[r] = __builtin_amdgcn_exp2f(v);
        }
        uint2 pk;
        pk.x = pack_trunc(p[0], p[1]);
        pk.y = pack_trunc(p[2], p[3]);
        *(uint2*)&ps[low * 72 + st * 16 + quad * 4] = pk;
    }
}

__device__ __forceinline__ void pv_step(
    const bf16x8 vf[4][2], const unsigned short* ps, int quad, int low,
    f32x4* o, f32x4& lacc, const bf16x8 ones)
{
    const bf16x8 p0 = *(const bf16x8*)&ps[low * 72 + quad * 8];
    const bf16x8 p1 = *(const bf16x8*)&ps[low * 72 + quad * 8 + 32];
    #pragma unroll
    for (int t = 0; t < 4; ++t) {
        o[t] = __builtin_amdgcn_mfma_f32_16x16x32_bf16(p0, vf[t][0], o[t], 0, 0, 0);
        o[t] = __builtin_amdgcn_mfma_f32_16x16x32_bf16(p1, vf[t][1], o[t], 0, 0, 0);
    }
    lacc = __builtin_amdgcn_mfma_f32_16x16x32_bf16(p0, ones, lacc, 0, 0, 0);
    lacc = __builtin_amdgcn_mfma_f32_16x16x32_bf16(p1, ones, lacc, 0, 0, 0);
}

__global__ __launch_bounds__(256) void attn_mfma(
    const unsigned short* __restrict__ qkv,   // bf16 [8192][1536]
    unsigned short* __restrict__ y)           // bf16 [8192][512]
{
    const int bh  = blockIdx.x & 31;          // same-bh blocks -> same XCD
    const int pa  = blockIdx.x >> 5;          // 0..15
    const int b   = bh >> 3, h = bh & 7;
    const int qA0 = pa * 64;
    const int qB0 = (31 - pa) * 64;
    const int nA  = pa + 1, nB = 32 - pa;
    const int tid = threadIdx.x;
    const int wave = tid >> 6, lane = tid & 63;
    const int low  = lane & 15, quad = lane >> 4;

    __shared__ unsigned short Ks[2][64 * 64];
    __shared__ unsigned short Vt[2][64 * 64];
    __shared__ unsigned short PsA[4][16 * 72];
    __shared__ unsigned short PsB[4][16 * 72];

    const size_t base = (size_t)b * SEQ_T * QKV_LD + h * 64;
    const unsigned short* qp = qkv + base;
    const unsigned short* kp = qkv + base + 512;
    const unsigned short* vp = qkv + base + 1024;

    const int qmyA = qA0 + wave * 16 + low;
    const int qmyB = qB0 + wave * 16 + low;

    const bf16x8 qfA0 = scale_frag(*(const bf16x8*)(qp + (size_t)qmyA * QKV_LD + quad * 8), CL);
    const bf16x8 qfA1 = scale_frag(*(const bf16x8*)(qp + (size_t)qmyA * QKV_LD + quad * 8 + 32), CL);
    const bf16x8 qfB0 = scale_frag(*(const bf16x8*)(qp + (size_t)qmyB * QKV_LD + quad * 8), CL);
    const bf16x8 qfB1 = scale_frag(*(const bf16x8*)(qp + (size_t)qmyB * QKV_LD + quad * 8 + 32), CL);

    bf16x8 ones;
    #pragma unroll
    for (int i = 0; i < 8; ++i) ones[i] = (short)0x3F80;   // bf16 1.0

    const int d0 = wave * 8;
    unsigned short* psA = &PsA[wave][0];
    unsigned short* psB = &PsB[wave][0];

    bf16x8 vr0 = *(const bf16x8*)(vp + (size_t)lane * QKV_LD + d0);
    bf16x8 vr1 = *(const bf16x8*)(vp + (size_t)lane * QKV_LD + d0 + 32);
    {
        #pragma unroll
        for (int ii = 0; ii < 2; ++ii) {
            const int row = wave * 16 + ii * 8 + (lane >> 3);
            const int o   = (lane & 7) ^ (lane >> 3);
            gl_lds16(kp + (size_t)row * QKV_LD + o * 8, &Ks[0][(wave * 2 + ii) * 512]);
        }
        #pragma unroll
        for (int ii = 0; ii < 8; ++ii) {
            const int po = ((lane >> 3) ^ ii) * 8 + (lane & 7);
            Vt[0][((d0 + ii) << 6) + po]      = (unsigned short)vr0[ii];
            Vt[0][((d0 + 32 + ii) << 6) + po] = (unsigned short)vr1[ii];
        }
        if (nB > 1) {
            vr0 = *(const bf16x8*)(vp + (size_t)(64 + lane) * QKV_LD + d0);
            vr1 = *(const bf16x8*)(vp + (size_t)(64 + lane) * QKV_LD + d0 + 32);
        }
    }
    __syncthreads();

    f32x4 oA[4], oB[4], lA, lB;
    #pragma unroll
    for (int t = 0; t < 4; ++t) {
        oA[t] = (f32x4){0.f, 0.f, 0.f, 0.f};
        oB[t] = (f32x4){0.f, 0.f, 0.f, 0.f};
    }
    lA = (f32x4){0.f, 0.f, 0.f, 0.f};
    lB = (f32x4){0.f, 0.f, 0.f, 0.f};

    for (int kc = 0; kc < nB; ++kc) {
        const int cur = kc & 1;
        unsigned short* ksc = &Ks[cur][0];
        unsigned short* vtc = &Vt[cur][0];

        if (kc + 1 < nB) {
            const int key1 = (kc + 1) * 64;
            #pragma unroll
            for (int ii = 0; ii < 2; ++ii) {
                const int row = wave * 16 + ii * 8 + (lane >> 3);
                const int o   = (lane & 7) ^ (lane >> 3);
                gl_lds16(kp + (size_t)(key1 + row) * QKV_LD + o * 8,
                         &Ks[cur ^ 1][(wave * 2 + ii) * 512]);
            }
            unsigned short* vtn = &Vt[cur ^ 1][0];
            #pragma unroll
            for (int ii = 0; ii < 8; ++ii) {
                const int po = ((lane >> 3) ^ ii) * 8 + (lane & 7);
                vtn[((d0 + ii) << 6) + po]      = (unsigned short)vr0[ii];
                vtn[((d0 + 32 + ii) << 6) + po] = (unsigned short)vr1[ii];
            }
        }
        if (kc + 2 < nB) {
            const int key2 = (kc + 2) * 64;
            vr0 = *(const bf16x8*)(vp + (size_t)(key2 + lane) * QKV_LD + d0);
            vr1 = *(const bf16x8*)(vp + (size_t)(key2 + lane) * QKV_LD + d0 + 32);
        }

        const int key0 = kc * 64;
        bf16x8 kf[4][2];
        #pragma unroll
        for (int t = 0; t < 4; ++t)
            #pragma unroll
            for (int i = 0; i < 2; ++i)
                kf[t][i] = *(const bf16x8*)
                    &ksc[((t * 16 + low) << 6) + (((quad + 4 * i) ^ (low & 7)) << 3)];

        if (kc < nA) {
            if (kc == nA - 1)
                tile_step<true >(kf, qfA0, qfA1, qmyA - key0 - quad * 4, quad, low, psA);
            else
                tile_step<false>(kf, qfA0, qfA1, 0, quad, low, psA);
        }
        if (kc == nB - 1)
            tile_step<true >(kf, qfB0, qfB1, qmyB - key0 - quad * 4, quad, low, psB);
        else
            tile_step<false>(kf, qfB0, qfB1, 0, quad, low, psB);

        asm volatile("" ::: "memory");   // per-wave Ps: program order + fence

        bf16x8 vf[4][2];
        #pragma unroll
        for (int t = 0; t < 4; ++t)
            #pragma unroll
            for (int i = 0; i < 2; ++i)
                vf[t][i] = *(const bf16x8*)
                    &vtc[((t * 16 + low) << 6) + (((quad + 4 * i) ^ (low & 7)) << 3)];

        if (kc < nA) pv_step(vf, psA, quad, low, oA, lA, ones);
        pv_step(vf, psB, quad, low, oB, lB, ones);
        __syncthreads();
    }

    #pragma unroll
    for (int r = 0; r < 4; ++r) {
        const float rlA = 1.f / lA[r];
        const int qrow = qA0 + wave * 16 + quad * 4 + r;
        unsigned short* yp = y + (size_t)(b * SEQ_T + qrow) * N_EMBD + h * 64 + low;
        #pragma unroll
        for (int t = 0; t < 4; ++t) yp[16 * t] = f2bf(oA[t][r] * rlA);
    }
    #pragma unroll
    for (int r = 0; r < 4; ++r) {
        const float rlB = 1.f / lB[r];
        const int qrow = qB0 + wave * 16 + quad * 4 + r;
        unsigned short* yp = y + (size_t)(b * SEQ_T + qrow) * N_EMBD + h * 64 + low;
        #pragma unroll
        for (int t = 0; t < 4; ++t) yp[16 * t] = f2bf(oB[t][r] * rlB);
    }
}

// ---------------------------------------------------------------------------
extern "C" void kernel_launch(void* const* d_in, const int* in_sizes, int n_in,
                              void* d_out, int out_size, void* d_ws, size_t ws_size,
                              hipStream_t stream)
{
    const float* x      = (const float*)d_in[0];
    const float* attn_w = (const float*)d_in[1];   // [512][1536]
    const float* attn_b = (const float*)d_in[2];
    const float* proj_w = (const float*)d_in[3];   // [512][512]
    const float* proj_b = (const float*)d_in[4];
    float*       out    = (float*)d_out;

    char* ws = (char*)d_ws;
    unsigned short* qkv_bf = (unsigned short*)(ws);                      // 25.2 MB
    unsigned short* y_bf   = (unsigned short*)(ws + 25165824);           //  8.4 MB
    unsigned short* w1t    = (unsigned short*)(ws + 33554432);           //  1.6 MB
    unsigned short* w2t    = (unsigned short*)(ws + 35127296);           //  0.5 MB

    prep<<<1024, 256, 0, stream>>>(attn_w, w1t, proj_w, w2t);

    // qkv = x(fp32, converted in-staging) @ w1t^T + b
    // 768 blocks = 8 XCD x (8 row-slabs x 12 col-tiles); per-XCD: 2MB x + 1.5MB w in L2
    gemm_mfma<128, 128, true, true><<<dim3(768), 256, 0, stream>>>(
        x, w1t, attn_b, qkv_bf, QKV_LD, N_EMBD, 8);

    attn_mfma<<<dim3(512), 256, 0, stream>>>(qkv_bf, y_bf);

    // 512 blocks = 8 XCD x (16 row-slabs x 4 col-tiles); per-XCD: 1MB y + 0.5MB w in L2
    gemm_mfma<64, 128, false, false><<<dim3(512), 256, 0, stream>>>(
        y_bf, w2t, proj_b, out, N_EMBD, N_EMBD, 16);
}